// Round 18
// baseline (127.161 us; speedup 1.0000x reference)
//
#include <hip/hip_runtime.h>
#include <math.h>

#define E_EDGES 4096
#define N_NODES 1024
#define D_NODE 128
#define D_EDGE 256
#define HEADS 4
#define HD 64
#define N_CLASSES 16
#define CAP 128   // max adjacent edges per edge (avg ~16, worst ~50)

typedef __attribute__((ext_vector_type(8))) short short8v;  // 8 bf16 = 4 VGPR
typedef __attribute__((ext_vector_type(4))) short short4v;  // 4 bf16 = 2 VGPR
typedef __attribute__((ext_vector_type(4))) float f32x4;    // MFMA C/D frag

__device__ __forceinline__ unsigned short f2bf(float f) {
    unsigned u = __float_as_uint(f);
    return (unsigned short)((u + 0x7FFFu + ((u >> 16) & 1u)) >> 16);
}
__device__ __forceinline__ float bf2f(unsigned short b) {
    return __uint_as_float(((unsigned)b) << 16);
}

// direct-to-LDS 16B DMA (gfx950): per-wave dest = uniform base + lane*16.
__device__ __forceinline__ void gload_lds16(const void* g, void* l) {
    __builtin_amdgcn_global_load_lds((const __attribute__((address_space(1))) void*)g,
                                     (__attribute__((address_space(3))) void*)l, 16, 0, 0);
}

// ---------------------------------------------------------------------------
// Weight-split unit: one 64x64 tile of one f32 W[k][n] -> TRANSPOSED bf16
// hi/lo WT[n][k], coalesced via LDS transpose. Uses smem[0..16639].
// ---------------------------------------------------------------------------
__device__ __forceinline__ void split_unit(
    char* smem, const float* __restrict__ W, short* __restrict__ ho,
    short* __restrict__ lo, int tile)
{
    float* tl = (float*)smem;   // [64][65]
    const int t = threadIdx.x;
    const int k0 = (tile >> 2) * 64, n0 = (tile & 3) * 64;
#pragma unroll
    for (int p = 0; p < 4; ++p) {
        const int kr = (t >> 4) + p * 16;
        const int nc = (t & 15) * 4;
        *(float4*)&tl[kr * 65 + nc] = *(const float4*)&W[(size_t)(k0 + kr) * 256 + n0 + nc];
    }
    __syncthreads();
    const int n = t >> 2, ks = (t & 3) * 16;
    short8v h0, h1, l0, l1;
#pragma unroll
    for (int j = 0; j < 8; ++j) {
        const float x = tl[(ks + j) * 65 + n];
        const unsigned short hb = f2bf(x);
        h0[j] = (short)hb; l0[j] = (short)f2bf(x - bf2f(hb));
    }
#pragma unroll
    for (int j = 0; j < 8; ++j) {
        const float x = tl[(ks + 8 + j) * 65 + n];
        const unsigned short hb = f2bf(x);
        h1[j] = (short)hb; l1[j] = (short)f2bf(x - bf2f(hb));
    }
    *(short8v*)&ho[(size_t)(n0 + n) * 256 + k0 + ks] = h0;
    *(short8v*)&ho[(size_t)(n0 + n) * 256 + k0 + ks + 8] = h1;
    *(short8v*)&lo[(size_t)(n0 + n) * 256 + k0 + ks] = l0;
    *(short8v*)&lo[(size_t)(n0 + n) * 256 + k0 + ks + 8] = l1;
}

// ---------------------------------------------------------------------------
// Adjacency unit: one wave builds edge e's CSR list (ballot-compaction asc).
// ---------------------------------------------------------------------------
__device__ __forceinline__ void adj_unit(
    const int* __restrict__ src, const int* __restrict__ dst,
    int* __restrict__ cand, int* __restrict__ ccount, int e, int lane)
{
    const int a = src[e], b = dst[e];
    int* my = cand + (size_t)e * CAP;
    int base = 0;
    for (int c0 = 0; c0 < E_EDGES; c0 += 64) {
        const int f = c0 + lane;
        const int sf = src[f], df = dst[f];
        const bool adj = (sf == a) | (sf == b) | (df == a) | (df == b);
        const unsigned long long mk = __ballot(adj);
        if (adj) {
            const int pos = base + __popcll(mk & ((1ull << lane) - 1ull));
            if (pos < CAP) my[pos] = f;
        }
        base += __popcll(mk);
    }
    if (lane == 0) ccount[e] = (base < CAP) ? base : CAP;
}

// ---------------------------------------------------------------------------
// Split-bf16 MFMA GEMM core, BM=32 (R13/R15-proven).
// C[32x64] = act((A[+A2])@B + bias + r1 + r2), K=256.
// A@B = AhBh + AhBl + AlBh. 4 waves (2x2), wave = 16x32 out, 6 MFMAs/K-tile
// in 2 independent acc chains. LDS 26.6KB. Dbuf, ONE barrier/K-tile;
// A loads before MFMA, split after (T14); B via global_load_lds DMA.
// If nf: A row m = concat(nf[src[m]], nf[dst[m]]).
// ---------------------------------------------------------------------------
__device__ __forceinline__ void mcore32(
    char* smem,
    const float* __restrict__ A, const float* __restrict__ A2,
    const short* __restrict__ BhiT, const short* __restrict__ BloT,
    const float* __restrict__ bias, const float* __restrict__ res,
    const float* __restrict__ res2, float* __restrict__ C,
    int m0, int n0,
    const float* __restrict__ nf, const int* __restrict__ src,
    const int* __restrict__ dst, int act)
{
    short* AsH = (short*)smem;              // [2][32*40]  5120 B
    short* AsL = (short*)(smem + 5120);     //             5120 B
    short* BsH = (short*)(smem + 10240);    // [2][64*32]  8192 B
    short* BsL = (short*)(smem + 18432);    //             8192 B -> 26624
    const int t = threadIdx.x;
    const int w = t >> 6, lane = t & 63, lr = lane & 15, lg = lane >> 4;
    const int WR = (w >> 1) * 16, WC = (w & 1) * 32;
    const int ar = t >> 3, akc = (t & 7) * 4;   // A stage: row, k-col
    const int bn = t >> 2, bkc = (t & 3) * 8;   // B DMA: n-row, k-col

    int nS = 0, nD = 0;
    if (nf) { nS = src[m0 + ar]; nD = dst[m0 + ar]; }

    f32x4 acc0 = {0.f, 0.f, 0.f, 0.f}, acc1 = {0.f, 0.f, 0.f, 0.f};
    float4 av;

#define LOADA_R(k0)                                                            \
    do {                                                                       \
        const int kq = (k0) + akc;                                             \
        if (nf) {                                                              \
            const float* pp = (kq < D_NODE)                                    \
                ? &nf[(size_t)nS * D_NODE + kq]                                \
                : &nf[(size_t)nD * D_NODE + kq - D_NODE];                      \
            av = *(const float4*)pp;                                           \
        } else {                                                               \
            av = *(const float4*)&A[(size_t)(m0 + ar) * 256 + kq];             \
            if (A2) {                                                          \
                const float4 c_ = *(const float4*)&A2[(size_t)(m0 + ar) * 256 + kq]; \
                av.x += c_.x; av.y += c_.y; av.z += c_.z; av.w += c_.w;        \
            }                                                                  \
        }                                                                      \
    } while (0)
#define STOREA_S(buf)                                                          \
    do {                                                                       \
        short4v ah, al;                                                        \
        const float fv[4] = {av.x, av.y, av.z, av.w};                          \
        _Pragma("unroll") for (int j = 0; j < 4; ++j) {                        \
            const unsigned short hb = f2bf(fv[j]);                             \
            ah[j] = (short)hb; al[j] = (short)f2bf(fv[j] - bf2f(hb));          \
        }                                                                      \
        *(short4v*)&AsH[(buf) * 1280 + ar * 40 + akc] = ah;                    \
        *(short4v*)&AsL[(buf) * 1280 + ar * 40 + akc] = al;                    \
    } while (0)
#define STAGE_B(buf, k0)                                                       \
    do {                                                                       \
        gload_lds16(&BhiT[(size_t)(n0 + bn) * 256 + (k0) + bkc],               \
                    BsH + (buf) * 2048 + t * 8);                               \
        gload_lds16(&BloT[(size_t)(n0 + bn) * 256 + (k0) + bkc],               \
                    BsL + (buf) * 2048 + t * 8);                               \
    } while (0)
#define MFMA_STEP(buf)                                                         \
    do {                                                                       \
        const int c0 = WC + lr, c1 = WC + 16 + lr;                             \
        const short8v bH0 = *(const short8v*)&BsH[(buf) * 2048 + c0 * 32 + lg * 8]; \
        const short8v bL0 = *(const short8v*)&BsL[(buf) * 2048 + c0 * 32 + lg * 8]; \
        const short8v bH1 = *(const short8v*)&BsH[(buf) * 2048 + c1 * 32 + lg * 8]; \
        const short8v bL1 = *(const short8v*)&BsL[(buf) * 2048 + c1 * 32 + lg * 8]; \
        const short8v aH = *(const short8v*)&AsH[(buf) * 1280 + (WR + lr) * 40 + lg * 8]; \
        const short8v aL = *(const short8v*)&AsL[(buf) * 1280 + (WR + lr) * 40 + lg * 8]; \
        acc0 = __builtin_amdgcn_mfma_f32_16x16x32_bf16(aH, bH0, acc0, 0, 0, 0);\
        acc1 = __builtin_amdgcn_mfma_f32_16x16x32_bf16(aH, bH1, acc1, 0, 0, 0);\
        acc0 = __builtin_amdgcn_mfma_f32_16x16x32_bf16(aH, bL0, acc0, 0, 0, 0);\
        acc1 = __builtin_amdgcn_mfma_f32_16x16x32_bf16(aH, bL1, acc1, 0, 0, 0);\
        acc0 = __builtin_amdgcn_mfma_f32_16x16x32_bf16(aL, bH0, acc0, 0, 0, 0);\
        acc1 = __builtin_amdgcn_mfma_f32_16x16x32_bf16(aL, bH1, acc1, 0, 0, 0);\
    } while (0)

    LOADA_R(0);
    STAGE_B(0, 0);
    STOREA_S(0);
    __syncthreads();

    for (int kt = 0; kt < 8; ++kt) {       // K = 256 = 8 x 32
        const int cur = kt & 1;
        if (kt < 7) {
            STAGE_B(cur ^ 1, (kt + 1) * 32);
            LOADA_R((kt + 1) * 32);
        }
        MFMA_STEP(cur);
        if (kt < 7) STOREA_S(cur ^ 1);
        __syncthreads();
    }

#define EPI(accv, ct)                                                          \
    do {                                                                       \
        const int col = n0 + WC + (ct) * 16 + lr;                              \
        const float bb = bias ? bias[col] : 0.f;                               \
        _Pragma("unroll") for (int i = 0; i < 4; ++i) {                        \
            const int row = m0 + WR + lg * 4 + i;                              \
            float v = accv[i] + bb;                                            \
            if (res)  v += res[(size_t)row * D_EDGE + col];                    \
            if (res2) v += res2[(size_t)row * D_EDGE + col];                   \
            if (act == 1) v = 0.5f * v * (1.f + erff(v * 0.70710678118654752f)); \
            C[(size_t)row * D_EDGE + col] = v;                                 \
        }                                                                      \
    } while (0)
    EPI(acc0, 0); EPI(acc1, 1);
#undef LOADA_R
#undef STOREA_S
#undef STAGE_B
#undef MFMA_STEP
#undef EPI
}

// ---------------------------------------------------------------------------
// Dispatch A: adjacency (blocks 0..1023, wave per edge) + Wn1/Wn2 splits
// (blocks 1024..1055) — only the splits ctx needs.
// ---------------------------------------------------------------------------
__global__ __launch_bounds__(256) void adj_prep(
    const int* __restrict__ src, const int* __restrict__ dst,
    int* __restrict__ cand, int* __restrict__ ccount,
    const float* Wn1, const float* Wn2, short* hiT, short* loT)
{
    __shared__ __attribute__((aligned(16))) char smem[16640];
    if (blockIdx.x < 1024) {
        const int t = threadIdx.x;
        adj_unit(src, dst, cand, ccount, blockIdx.x * 4 + (t >> 6), t & 63);
    } else {
        const int u = blockIdx.x - 1024;
        const int mat = (u >> 4) ? 5 : 0;
        split_unit(smem, (u >> 4) ? Wn2 : Wn1,
                   hiT + (size_t)mat * 65536, loT + (size_t)mat * 65536, u & 15);
    }
}

// ---------------------------------------------------------------------------
// Dispatch B: ctx both layers (blocks 0..1023, XCD row-panel pinned) + the
// 9 remaining weight splits (blocks 1024..1167). (R15-verbatim — the R16/R17
// x-materialization rewiring ICE'd clang and is abandoned.)
// ---------------------------------------------------------------------------
__global__ __launch_bounds__(256) void ctx_prep(
    const float* __restrict__ nf, const int* __restrict__ src,
    const int* __restrict__ dst, short* hiT, short* loT,
    const float* __restrict__ bn1, const float* __restrict__ bn2,
    float* __restrict__ ctx,
    const float* Wq1, const float* Wk1, const float* Wv1, const float* Wo1,
    const float* Wq2, const float* Wk2, const float* Wv2, const float* Wo2,
    const float* Wc1)
{
    __shared__ __attribute__((aligned(16))) char smem[26624];
    if (blockIdx.x < 1024) {
        const int lid = blockIdx.x;
        const int g = lid & 7, s = lid >> 3;       // XCD, slot
        const int rowt = g * 32 + (s >> 2);        // [0,256)
        const int ct = s & 3;
        const int R = rowt * 32;
        const int Lyr = R >> 12;
        const int r = R & (E_EDGES - 1);
        mcore32(smem, nullptr, nullptr,
                hiT + (size_t)(Lyr * 5) * 65536, loT + (size_t)(Lyr * 5) * 65536,
                Lyr ? bn2 : bn1, nullptr, nullptr,
                ctx + (size_t)Lyr * E_EDGES * D_EDGE,
                r, ct * 64, nf, src, dst, 0);
    } else {
        const int u = blockIdx.x - 1024;
        const int mi = u >> 4;
        const int matIdx[9] = {1, 2, 3, 4, 6, 7, 8, 9, 10};
        const float* Ws[9] = {Wq1, Wk1, Wv1, Wo1, Wq2, Wk2, Wv2, Wo2, Wc1};
        const int mat = matIdx[mi];
        split_unit(smem, Ws[mi], hiT + (size_t)mat * 65536,
                   loT + (size_t)mat * 65536, u & 15);
    }
}

// q/k/v fused: 1536 blocks = one 6/CU pass; row-panel pinned to one XCD.
__global__ __launch_bounds__(256) void gemm_qkv32(
    const float* __restrict__ ef_in, const float* __restrict__ ctx,
    const short* __restrict__ whiT, const short* __restrict__ wloT,
    const float* __restrict__ bq, const float* __restrict__ bk,
    const float* __restrict__ bv,
    float* __restrict__ qb, float* __restrict__ kb, float* __restrict__ vb,
    int wbase)
{
    __shared__ __attribute__((aligned(16))) char smem[26624];
    const int lid = blockIdx.x;
    const int g = lid & 7, s = lid >> 3;           // s in [0,192)
    const int rowt = g * 16 + s / 12;              // [0,128)
    const int rem = s % 12, wsel = rem >> 2, ct = rem & 3;
    const short* BH = whiT + (size_t)(wbase + 1 + wsel) * 65536;
    const short* BL = wloT + (size_t)(wbase + 1 + wsel) * 65536;
    const float* bias = (wsel == 0) ? bq : (wsel == 1) ? bk : bv;
    float* C = (wsel == 0) ? qb : (wsel == 1) ? kb : vb;
    mcore32(smem, ef_in, ctx, BH, BL, bias, nullptr, nullptr, C,
            rowt * 32, ct * 64, nullptr, nullptr, nullptr, 0);
}

// Generic 512-block GEMM: C = act(A@B + bias + res + res2).
__global__ __launch_bounds__(256) void gemm_g32(
    const float* __restrict__ A, const short* __restrict__ BhiT,
    const short* __restrict__ BloT, const float* __restrict__ bias,
    const float* __restrict__ res, const float* __restrict__ res2,
    float* __restrict__ C, int act)
{
    __shared__ __attribute__((aligned(16))) char smem[26624];
    const int lid = blockIdx.x;
    const int g = lid & 7, s = lid >> 3;           // s in [0,64)
    const int rowt = g * 16 + (s >> 2);            // [0,128)
    const int ct = s & 3;
    mcore32(smem, A, nullptr, BhiT, BloT, bias, res, res2, C,
            rowt * 32, ct * 64, nullptr, nullptr, nullptr, act);
}

// ---------------------------------------------------------------------------
// Sparse attention v6: R15's v5 (wave = edge, 16-lane group = head, no
// cross-group merge) with a 4-WAY unrolled candidate loop — 4 independent
// shfl-reduce chains, ONE joint max + rescale per 4 candidates (halves the
// serial online-softmax update count vs 2-way).
// ---------------------------------------------------------------------------
__global__ __launch_bounds__(256) void attn_sparse6(
    const float* __restrict__ q, const float* __restrict__ k,
    const float* __restrict__ v, const int* __restrict__ cand,
    const int* __restrict__ ccount, float* __restrict__ out)
{
    __shared__ int lc[4][CAP];
    const int t = threadIdx.x;
    const int w = t >> 6, lane = t & 63;
    const int e = blockIdx.x * 4 + w;
    const int h = lane >> 4, il = lane & 15;
    const int m = ccount[e];
    for (int i = lane; i < m; i += 64) lc[w][i] = cand[(size_t)e * CAP + i];

    const float4 q4 = *(const float4*)&q[(size_t)e * D_EDGE + h * HD + il * 4];
    float M = -1e30f, L = 0.f;
    float4 O = make_float4(0.f, 0.f, 0.f, 0.f);

    int i = 0;
    for (; i + 4 <= m; i += 4) {
        const int f0 = lc[w][i], f1 = lc[w][i + 1];
        const int f2 = lc[w][i + 2], f3 = lc[w][i + 3];
        const float4 k0 = *(const float4*)&k[(size_t)f0 * D_EDGE + h * HD + il * 4];
        const float4 v0 = *(const float4*)&v[(size_t)f0 * D_EDGE + h * HD + il * 4];
        const float4 k1 = *(const float4*)&k[(size_t)f1 * D_EDGE + h * HD + il * 4];
        const float4 v1 = *(const float4*)&v[(size_t)f1 * D_EDGE + h * HD + il * 4];
        const float4 k2 = *(const float4*)&k[(size_t)f2 * D_EDGE + h * HD + il * 4];
        const float4 v2 = *(const float4*)&v[(size_t)f2 * D_EDGE + h * HD + il * 4];
        const float4 k3 = *(const float4*)&k[(size_t)f3 * D_EDGE + h * HD + il * 4];
        const float4 v3 = *(const float4*)&v[(size_t)f3 * D_EDGE + h * HD + il * 4];
        float s0 = q4.x * k0.x + q4.y * k0.y + q4.z * k0.z + q4.w * k0.w;
        float s1 = q4.x * k1.x + q4.y * k1.y + q4.z * k1.z + q4.w * k1.w;
        float s2 = q4.x * k2.x + q4.y * k2.y + q4.z * k2.z + q4.w * k2.w;
        float s3 = q4.x * k3.x + q4.y * k3.y + q4.z * k3.z + q4.w * k3.w;
        s0 += __shfl_xor(s0, 1); s1 += __shfl_xor(s1, 1);
        s2 += __shfl_xor(s2, 1); s3 += __shfl_xor(s3, 1);
        s0 += __shfl_xor(s0, 2); s1 += __shfl_xor(s1, 2);
        s2 += __shfl_xor(s2, 2); s3 += __shfl_xor(s3, 2);
        s0 += __shfl_xor(s0, 4); s1 += __shfl_xor(s1, 4);
        s2 += __shfl_xor(s2, 4); s3 += __shfl_xor(s3, 4);
        s0 += __shfl_xor(s0, 8); s1 += __shfl_xor(s1, 8);
        s2 += __shfl_xor(s2, 8); s3 += __shfl_xor(s3, 8);
        s0 *= 0.125f; s1 *= 0.125f; s2 *= 0.125f; s3 *= 0.125f;
        const float m01 = fmaxf(s0, s1), m23 = fmaxf(s2, s3);
        const float Mn = fmaxf(M, fmaxf(m01, m23));
        const float al = __expf(M - Mn);
        const float p0 = __expf(s0 - Mn), p1 = __expf(s1 - Mn);
        const float p2 = __expf(s2 - Mn), p3 = __expf(s3 - Mn);
        O.x = O.x * al + p0 * v0.x + p1 * v1.x + p2 * v2.x + p3 * v3.x;
        O.y = O.y * al + p0 * v0.y + p1 * v1.y + p2 * v2.y + p3 * v3.y;
        O.z = O.z * al + p0 * v0.z + p1 * v1.z + p2 * v2.z + p3 * v3.z;
        O.w = O.w * al + p0 * v0.w + p1 * v1.w + p2 * v2.w + p3 * v3.w;
        L = L * al + (p0 + p1) + (p2 + p3);
        M = Mn;
    }
    for (; i < m; ++i) {
        const int f = lc[w][i];
        const float4 kv = *(const float4*)&k[(size_t)f * D_EDGE + h * HD + il * 4];
        const float4 vv = *(const float4*)&v[(size_t)f * D_EDGE + h * HD + il * 4];
        float s = q4.x * kv.x + q4.y * kv.y + q4.z * kv.z + q4.w * kv.w;
        s += __shfl_xor(s, 1);
        s += __shfl_xor(s, 2);
        s += __shfl_xor(s, 4);
        s += __shfl_xor(s, 8);
        s *= 0.125f;
        const float Mn = fmaxf(M, s);
        const float al = __expf(M - Mn);
        const float p = __expf(s - Mn);
        O.x = O.x * al + p * vv.x;
        O.y = O.y * al + p * vv.y;
        O.z = O.z * al + p * vv.z;
        O.w = O.w * al + p * vv.w;
        L = L * al + p;
        M = Mn;
    }
    const float invL = 1.f / L;
    float4 r = make_float4(O.x * invL, O.y * invL, O.z * invL, O.w * invL);
    *(float4*)&out[(size_t)e * D_EDGE + h * HD + il * 4] = r;
}

// ---------------------------------------------------------------------------
// Fused classifier (R11/R15-proven): out = gelu(y@W1+b1)@W2 + b2.
// 256 blocks x 16-row tiles, LDS 35KB -> 4 blocks/CU.
// ---------------------------------------------------------------------------
__global__ __launch_bounds__(256) void gemm_cls(
    const float* __restrict__ y, const short* __restrict__ BhiT,
    const short* __restrict__ BloT, const float* __restrict__ b1,
    const float* __restrict__ W2, const float* __restrict__ b2,
    float* __restrict__ outp)
{
    __shared__ __attribute__((aligned(16))) char smem[35840];
    short* AsH = (short*)smem;                  // 16*40 sh = 1280 B
    short* AsL = (short*)(smem + 1280);
    short* BsH = (short*)(smem + 2560);         // 256*32 sh = 16384 B
    short* BsL = (short*)(smem + 18944);        // -> 35328
    short* hH  = (short*)smem;                  // 16*264 sh = 8448 B (ph 2)
    short* hL  = (short*)(smem + 8448);
    float* W2s = (float*)(smem + 16896);        // 16384 -> 33280

    const int t = threadIdx.x;
    const int w = t >> 6, lane = t & 63, lr = lane & 15, lg = lane >> 4;
    const int m0 = blockIdx.x * 16;

    f32x4 acc[4];
#pragma unroll
    for (int ct = 0; ct < 4; ++ct) acc[ct] = (f32x4){0.f, 0.f, 0.f, 0.f};

    for (int kt = 0; kt < 8; ++kt) {
        const int k0 = kt * 32;
        if (t < 128) {
            const int row = t >> 3, kc = (t & 7) * 4;
            const float4 a4 = *(const float4*)&y[(size_t)(m0 + row) * 256 + k0 + kc];
            const float fv[4] = {a4.x, a4.y, a4.z, a4.w};
#pragma unroll
            for (int j = 0; j < 4; ++j) {
                const unsigned short hb = f2bf(fv[j]);
                AsH[row * 40 + kc + j] = (short)hb;
                AsL[row * 40 + kc + j] = (short)f2bf(fv[j] - bf2f(hb));
            }
        }
#pragma unroll
        for (int p = 0; p < 4; ++p) {
            const int idx = t + 256 * p;
            const int n = idx >> 2, k8 = (idx & 3) * 8;
            gload_lds16(&BhiT[(size_t)n * 256 + k0 + k8], BsH + (size_t)idx * 8);
            gload_lds16(&BloT[(size_t)n * 256 + k0 + k8], BsL + (size_t)idx * 8);
        }
        __syncthreads();
        const short8v aH = *(const short8v*)&AsH[lr * 40 + lg * 8];
        const short8v aL = *(const short8v*)&AsL[lr * 40 + lg * 8];
#pragma unroll
        for (int ct = 0; ct < 4; ++ct) {
            const int c = w * 64 + ct * 16 + lr;
            const short8v bH = *(const short8v*)&BsH[c * 32 + lg * 8];
            const short8v bL = *(const short8v*)&BsL[c * 32 + lg * 8];
            acc[ct] = __builtin_amdgcn_mfma_f32_16x16x32_bf16(aH, bH, acc[ct], 0, 0, 0);
            acc[ct] = __builtin_amdgcn_mfma_f32_16x16x32_bf16(aH, bL, acc[ct], 0, 0, 0);
            acc[ct] = __builtin_amdgcn_mfma_f32_16x16x32_bf16(aL, bH, acc[ct], 0, 0, 0);
        }
        __syncthreads();
    }

#pragma unroll
    for (int ct = 0; ct < 4; ++ct) {
        const int col = w * 64 + ct * 16 + lr;
        const float bb = b1[col];
#pragma unroll
        for (int i = 0; i < 4; ++i) {
            const int row = lg * 4 + i;
            float vv = acc[ct][i] + bb;
            vv = 0.5f * vv * (1.f + erff(vv * 0.70710678118654752f));
            const unsigned short hb = f2bf(vv);
            hH[row * 264 + col] = (short)hb;
            hL[row * 264 + col] = (short)f2bf(vv - bf2f(hb));
        }
    }
#pragma unroll
    for (int p = 0; p < 4; ++p) {
        const int idx = t + 256 * p;
        gload_lds16(&W2[(size_t)idx * 4], W2s + (size_t)idx * 4);
    }
    __syncthreads();

    f32x4 o = {0.f, 0.f, 0.f, 0.f};
#pragma unroll
    for (int kk = 0; kk < 8; ++kk) {
        const short8v aH = *(const short8v*)&hH[lr * 264 + kk * 32 + lg * 8];
        const short8v aL = *(const short8v*)&hL[lr * 264 + kk * 32 + lg * 8];
        short8v bH, bL;
#pragma unroll
        for (int j = 0; j < 8; ++j) {
            const float x = W2s[(size_t)(kk * 32 + lg * 8 + j) * 16 + lr];
            const unsigned short hb = f2bf(x);
            bH[j] = (short)hb; bL[j] = (short)f2bf(x - bf2f(hb));
        }
        o = __builtin_amdgcn_mfma_f32_16x16x32_bf16(aH, bH, o, 0, 0, 0);
        o = __builtin_amdgcn_mfma_f32_16x16x32_bf16(aH, bL, o, 0, 0, 0);
        o = __builtin_amdgcn_mfma_f32_16x16x32_bf16(aL, bH, o, 0, 0, 0);
    }
    if (w == 0) {
#pragma unroll
        for (int i = 0; i < 4; ++i) {
            const int row = m0 + lg * 4 + i;
            outp[(size_t)row * 16 + lr] = o[i] + b2[lr];
        }
    }
}

// ---------------------------------------------------------------------------
extern "C" void kernel_launch(void* const* d_in, const int* in_sizes, int n_in,
                              void* d_out, int out_size, void* d_ws, size_t ws_size,
                              hipStream_t stream)
{
    const float* nf = (const float*)d_in[0];
    const float* ef = (const float*)d_in[1];
    const int* ei = (const int*)d_in[2];
    const int* src = ei;
    const int* dst = ei + E_EDGES;

    const float* a_Wn[2] = {(const float*)d_in[3],  (const float*)d_in[13]};
    const float* a_bn[2] = {(const float*)d_in[4],  (const float*)d_in[14]};
    const float* a_Wq[2] = {(const float*)d_in[5],  (const float*)d_in[15]};
    const float* a_bq[2] = {(const float*)d_in[6],  (const float*)d_in[16]};
    const float* a_Wk[2] = {(const float*)d_in[7],  (const float*)d_in[17]};
    const float* a_bk[2] = {(const float*)d_in[8],  (const float*)d_in[18]};
    const float* a_Wv[2] = {(const float*)d_in[9],  (const float*)d_in[19]};
    const float* a_bv[2] = {(const float*)d_in[10], (const float*)d_in[20]};
    const float* a_Wo[2] = {(const float*)d_in[11], (const float*)d_in[21]};
    const float* a_bo[2] = {(const float*)d_in[12], (const float*)d_in[22]};
    const float* cls_W1 = (const float*)d_in[23];
    const float* cls_b1 = (const float*)d_in[24];
    const float* cls_W2 = (const float*)d_in[25];
    const float* cls_b2 = (const float*)d_in[26];

    const size_t buf = (size_t)E_EDGES * D_EDGE;  // 1M floats = 4MB
    float* ws = (float*)d_ws;
    float* ctx1 = ws + 0 * buf;         // ctx base; ctx2 contiguous
    float* ctx2 = ws + 1 * buf;
    float* qb   = ws + 2 * buf;
    float* kb   = ws + 3 * buf;
    float* vb   = ws + 4 * buf;
    float* ao   = ws + 5 * buf;
    float* y1   = ws + 6 * buf;
    float* y2   = ctx1;                 // ctx1 dead after layer-1 Wo
    int* cand   = (int*)(ws + 7 * buf);            // 4096*128*4 = 2MB
    int* ccount = cand + (size_t)E_EDGES * CAP;    // 16KB
    short* whiT = (short*)(ccount + E_EDGES);      // 11 x 128KB
    short* wloT = whiT + (size_t)11 * 65536;       // 11 x 128KB

    // A: adjacency + Wn splits (the only splits ctx needs)
    adj_prep<<<1056, 256, 0, stream>>>(src, dst, cand, ccount,
                                       a_Wn[0], a_Wn[1], whiT, wloT);
    // B: ctx both layers + the 9 remaining splits (first needed by qkv)
    ctx_prep<<<1168, 256, 0, stream>>>(nf, src, dst, whiT, wloT,
                                       a_bn[0], a_bn[1], ctx1,
                                       a_Wq[0], a_Wk[0], a_Wv[0], a_Wo[0],
                                       a_Wq[1], a_Wk[1], a_Wv[1], a_Wo[1],
                                       cls_W1);

    const float* ef_in = ef;
    const float* ctxL[2] = {ctx1, ctx2};
    float* yout[2] = {y1, y2};
    for (int L = 0; L < 2; ++L) {
        const int wbase = L * 5;
        gemm_qkv32<<<1536, 256, 0, stream>>>(
            ef_in, ctxL[L], whiT, wloT, a_bq[L], a_bk[L], a_bv[L],
            qb, kb, vb, wbase);
        attn_sparse6<<<E_EDGES / 4, 256, 0, stream>>>(qb, kb, vb, cand, ccount, ao);
        gemm_g32<<<512, 256, 0, stream>>>(
            ao, whiT + (size_t)(wbase + 4) * 65536,
            wloT + (size_t)(wbase + 4) * 65536,
            a_bo[L], ef_in, ctxL[L], yout[L], 0);
        ef_in = yout[L];
    }

    // classifier (fused): out = gelu(y2@W1+b1)@W2 + b2
    gemm_cls<<<E_EDGES / 16, 256, 0, stream>>>(
        y2, whiT + (size_t)10 * 65536, wloT + (size_t)10 * 65536,
        cls_b1, cls_W2, cls_b2, (float*)d_out);
}

// Round 19
// 126.783 us; speedup vs baseline: 1.0030x; 1.0030x over previous
//
#include <hip/hip_runtime.h>
#include <math.h>

#define E_EDGES 4096
#define N_NODES 1024
#define D_NODE 128
#define D_EDGE 256
#define HEADS 4
#define HD 64
#define N_CLASSES 16
#define CAP 128   // max adjacent edges per edge (avg ~16, worst ~50)

typedef __attribute__((ext_vector_type(8))) short short8v;  // 8 bf16 = 4 VGPR
typedef __attribute__((ext_vector_type(4))) short short4v;  // 4 bf16 = 2 VGPR
typedef __attribute__((ext_vector_type(4))) float f32x4;    // MFMA C/D frag

__device__ __forceinline__ unsigned short f2bf(float f) {
    unsigned u = __float_as_uint(f);
    return (unsigned short)((u + 0x7FFFu + ((u >> 16) & 1u)) >> 16);
}
__device__ __forceinline__ float bf2f(unsigned short b) {
    return __uint_as_float(((unsigned)b) << 16);
}

// direct-to-LDS 16B DMA (gfx950): per-wave dest = uniform base + lane*16.
__device__ __forceinline__ void gload_lds16(const void* g, void* l) {
    __builtin_amdgcn_global_load_lds((const __attribute__((address_space(1))) void*)g,
                                     (__attribute__((address_space(3))) void*)l, 16, 0, 0);
}

// ---------------------------------------------------------------------------
// Weight-split unit: one 64x64 tile of one f32 W[k][n] -> TRANSPOSED bf16
// hi/lo WT[n][k], coalesced via LDS transpose. Uses smem[0..16639].
// ---------------------------------------------------------------------------
__device__ __forceinline__ void split_unit(
    char* smem, const float* __restrict__ W, short* __restrict__ ho,
    short* __restrict__ lo, int tile)
{
    float* tl = (float*)smem;   // [64][65]
    const int t = threadIdx.x;
    const int k0 = (tile >> 2) * 64, n0 = (tile & 3) * 64;
#pragma unroll
    for (int p = 0; p < 4; ++p) {
        const int kr = (t >> 4) + p * 16;
        const int nc = (t & 15) * 4;
        *(float4*)&tl[kr * 65 + nc] = *(const float4*)&W[(size_t)(k0 + kr) * 256 + n0 + nc];
    }
    __syncthreads();
    const int n = t >> 2, ks = (t & 3) * 16;
    short8v h0, h1, l0, l1;
#pragma unroll
    for (int j = 0; j < 8; ++j) {
        const float x = tl[(ks + j) * 65 + n];
        const unsigned short hb = f2bf(x);
        h0[j] = (short)hb; l0[j] = (short)f2bf(x - bf2f(hb));
    }
#pragma unroll
    for (int j = 0; j < 8; ++j) {
        const float x = tl[(ks + 8 + j) * 65 + n];
        const unsigned short hb = f2bf(x);
        h1[j] = (short)hb; l1[j] = (short)f2bf(x - bf2f(hb));
    }
    *(short8v*)&ho[(size_t)(n0 + n) * 256 + k0 + ks] = h0;
    *(short8v*)&ho[(size_t)(n0 + n) * 256 + k0 + ks + 8] = h1;
    *(short8v*)&lo[(size_t)(n0 + n) * 256 + k0 + ks] = l0;
    *(short8v*)&lo[(size_t)(n0 + n) * 256 + k0 + ks + 8] = l1;
}

// ---------------------------------------------------------------------------
// Adjacency unit: one wave builds edge e's CSR list (ballot-compaction asc).
// ---------------------------------------------------------------------------
__device__ __forceinline__ void adj_unit(
    const int* __restrict__ src, const int* __restrict__ dst,
    int* __restrict__ cand, int* __restrict__ ccount, int e, int lane)
{
    const int a = src[e], b = dst[e];
    int* my = cand + (size_t)e * CAP;
    int base = 0;
    for (int c0 = 0; c0 < E_EDGES; c0 += 64) {
        const int f = c0 + lane;
        const int sf = src[f], df = dst[f];
        const bool adj = (sf == a) | (sf == b) | (df == a) | (df == b);
        const unsigned long long mk = __ballot(adj);
        if (adj) {
            const int pos = base + __popcll(mk & ((1ull << lane) - 1ull));
            if (pos < CAP) my[pos] = f;
        }
        base += __popcll(mk);
    }
    if (lane == 0) ccount[e] = (base < CAP) ? base : CAP;
}

// ---------------------------------------------------------------------------
// Split-bf16 MFMA GEMM core, BM=32 (R13/R15-proven).
// C[32x64] = act((A[+A2])@B + bias + r1 + r2), K=256.
// A@B = AhBh + AhBl + AlBh. 4 waves (2x2), wave = 16x32 out, 6 MFMAs/K-tile
// in 2 independent acc chains. LDS 26.6KB. Dbuf, ONE barrier/K-tile;
// A loads before MFMA, split after (T14); B via global_load_lds DMA.
// If nf: A row m = concat(nf[src[m]], nf[dst[m]]).
// ---------------------------------------------------------------------------
__device__ __forceinline__ void mcore32(
    char* smem,
    const float* __restrict__ A, const float* __restrict__ A2,
    const short* __restrict__ BhiT, const short* __restrict__ BloT,
    const float* __restrict__ bias, const float* __restrict__ res,
    const float* __restrict__ res2, float* __restrict__ C,
    int m0, int n0,
    const float* __restrict__ nf, const int* __restrict__ src,
    const int* __restrict__ dst, int act)
{
    short* AsH = (short*)smem;              // [2][32*40]  5120 B
    short* AsL = (short*)(smem + 5120);     //             5120 B
    short* BsH = (short*)(smem + 10240);    // [2][64*32]  8192 B
    short* BsL = (short*)(smem + 18432);    //             8192 B -> 26624
    const int t = threadIdx.x;
    const int w = t >> 6, lane = t & 63, lr = lane & 15, lg = lane >> 4;
    const int WR = (w >> 1) * 16, WC = (w & 1) * 32;
    const int ar = t >> 3, akc = (t & 7) * 4;   // A stage: row, k-col
    const int bn = t >> 2, bkc = (t & 3) * 8;   // B DMA: n-row, k-col

    int nS = 0, nD = 0;
    if (nf) { nS = src[m0 + ar]; nD = dst[m0 + ar]; }

    f32x4 acc0 = {0.f, 0.f, 0.f, 0.f}, acc1 = {0.f, 0.f, 0.f, 0.f};
    float4 av;

#define LOADA_R(k0)                                                            \
    do {                                                                       \
        const int kq = (k0) + akc;                                             \
        if (nf) {                                                              \
            const float* pp = (kq < D_NODE)                                    \
                ? &nf[(size_t)nS * D_NODE + kq]                                \
                : &nf[(size_t)nD * D_NODE + kq - D_NODE];                      \
            av = *(const float4*)pp;                                           \
        } else {                                                               \
            av = *(const float4*)&A[(size_t)(m0 + ar) * 256 + kq];             \
            if (A2) {                                                          \
                const float4 c_ = *(const float4*)&A2[(size_t)(m0 + ar) * 256 + kq]; \
                av.x += c_.x; av.y += c_.y; av.z += c_.z; av.w += c_.w;        \
            }                                                                  \
        }                                                                      \
    } while (0)
#define STOREA_S(buf)                                                          \
    do {                                                                       \
        short4v ah, al;                                                        \
        const float fv[4] = {av.x, av.y, av.z, av.w};                          \
        _Pragma("unroll") for (int j = 0; j < 4; ++j) {                        \
            const unsigned short hb = f2bf(fv[j]);                             \
            ah[j] = (short)hb; al[j] = (short)f2bf(fv[j] - bf2f(hb));          \
        }                                                                      \
        *(short4v*)&AsH[(buf) * 1280 + ar * 40 + akc] = ah;                    \
        *(short4v*)&AsL[(buf) * 1280 + ar * 40 + akc] = al;                    \
    } while (0)
#define STAGE_B(buf, k0)                                                       \
    do {                                                                       \
        gload_lds16(&BhiT[(size_t)(n0 + bn) * 256 + (k0) + bkc],               \
                    BsH + (buf) * 2048 + t * 8);                               \
        gload_lds16(&BloT[(size_t)(n0 + bn) * 256 + (k0) + bkc],               \
                    BsL + (buf) * 2048 + t * 8);                               \
    } while (0)
#define MFMA_STEP(buf)                                                         \
    do {                                                                       \
        const int c0 = WC + lr, c1 = WC + 16 + lr;                             \
        const short8v bH0 = *(const short8v*)&BsH[(buf) * 2048 + c0 * 32 + lg * 8]; \
        const short8v bL0 = *(const short8v*)&BsL[(buf) * 2048 + c0 * 32 + lg * 8]; \
        const short8v bH1 = *(const short8v*)&BsH[(buf) * 2048 + c1 * 32 + lg * 8]; \
        const short8v bL1 = *(const short8v*)&BsL[(buf) * 2048 + c1 * 32 + lg * 8]; \
        const short8v aH = *(const short8v*)&AsH[(buf) * 1280 + (WR + lr) * 40 + lg * 8]; \
        const short8v aL = *(const short8v*)&AsL[(buf) * 1280 + (WR + lr) * 40 + lg * 8]; \
        acc0 = __builtin_amdgcn_mfma_f32_16x16x32_bf16(aH, bH0, acc0, 0, 0, 0);\
        acc1 = __builtin_amdgcn_mfma_f32_16x16x32_bf16(aH, bH1, acc1, 0, 0, 0);\
        acc0 = __builtin_amdgcn_mfma_f32_16x16x32_bf16(aH, bL0, acc0, 0, 0, 0);\
        acc1 = __builtin_amdgcn_mfma_f32_16x16x32_bf16(aH, bL1, acc1, 0, 0, 0);\
        acc0 = __builtin_amdgcn_mfma_f32_16x16x32_bf16(aL, bH0, acc0, 0, 0, 0);\
        acc1 = __builtin_amdgcn_mfma_f32_16x16x32_bf16(aL, bH1, acc1, 0, 0, 0);\
    } while (0)

    LOADA_R(0);
    STAGE_B(0, 0);
    STOREA_S(0);
    __syncthreads();

    for (int kt = 0; kt < 8; ++kt) {       // K = 256 = 8 x 32
        const int cur = kt & 1;
        if (kt < 7) {
            STAGE_B(cur ^ 1, (kt + 1) * 32);
            LOADA_R((kt + 1) * 32);
        }
        MFMA_STEP(cur);
        if (kt < 7) STOREA_S(cur ^ 1);
        __syncthreads();
    }

#define EPI(accv, ct)                                                          \
    do {                                                                       \
        const int col = n0 + WC + (ct) * 16 + lr;                              \
        const float bb = bias ? bias[col] : 0.f;                               \
        _Pragma("unroll") for (int i = 0; i < 4; ++i) {                        \
            const int row = m0 + WR + lg * 4 + i;                              \
            float v = accv[i] + bb;                                            \
            if (res)  v += res[(size_t)row * D_EDGE + col];                    \
            if (res2) v += res2[(size_t)row * D_EDGE + col];                   \
            if (act == 1) v = 0.5f * v * (1.f + erff(v * 0.70710678118654752f)); \
            C[(size_t)row * D_EDGE + col] = v;                                 \
        }                                                                      \
    } while (0)
    EPI(acc0, 0); EPI(acc1, 1);
#undef LOADA_R
#undef STOREA_S
#undef STAGE_B
#undef MFMA_STEP
#undef EPI
}

// ---------------------------------------------------------------------------
// Dispatch A: adjacency (blocks 0..1023, wave per edge) + Wn1/Wn2 splits
// (blocks 1024..1055) — only the splits ctx needs.
// ---------------------------------------------------------------------------
__global__ __launch_bounds__(256) void adj_prep(
    const int* __restrict__ src, const int* __restrict__ dst,
    int* __restrict__ cand, int* __restrict__ ccount,
    const float* Wn1, const float* Wn2, short* hiT, short* loT)
{
    __shared__ __attribute__((aligned(16))) char smem[16640];
    if (blockIdx.x < 1024) {
        const int t = threadIdx.x;
        adj_unit(src, dst, cand, ccount, blockIdx.x * 4 + (t >> 6), t & 63);
    } else {
        const int u = blockIdx.x - 1024;
        const int mat = (u >> 4) ? 5 : 0;
        split_unit(smem, (u >> 4) ? Wn2 : Wn1,
                   hiT + (size_t)mat * 65536, loT + (size_t)mat * 65536, u & 15);
    }
}

// ---------------------------------------------------------------------------
// Dispatch B: ctx both layers (blocks 0..1023, XCD row-panel pinned) + the
// 9 remaining weight splits (blocks 1024..1167). (R15-verbatim — the R16/R17
// x-materialization rewiring ICE'd clang and is abandoned.)
// ---------------------------------------------------------------------------
__global__ __launch_bounds__(256) void ctx_prep(
    const float* __restrict__ nf, const int* __restrict__ src,
    const int* __restrict__ dst, short* hiT, short* loT,
    const float* __restrict__ bn1, const float* __restrict__ bn2,
    float* __restrict__ ctx,
    const float* Wq1, const float* Wk1, const float* Wv1, const float* Wo1,
    const float* Wq2, const float* Wk2, const float* Wv2, const float* Wo2,
    const float* Wc1)
{
    __shared__ __attribute__((aligned(16))) char smem[26624];
    if (blockIdx.x < 1024) {
        const int lid = blockIdx.x;
        const int g = lid & 7, s = lid >> 3;       // XCD, slot
        const int rowt = g * 32 + (s >> 2);        // [0,256)
        const int ct = s & 3;
        const int R = rowt * 32;
        const int Lyr = R >> 12;
        const int r = R & (E_EDGES - 1);
        mcore32(smem, nullptr, nullptr,
                hiT + (size_t)(Lyr * 5) * 65536, loT + (size_t)(Lyr * 5) * 65536,
                Lyr ? bn2 : bn1, nullptr, nullptr,
                ctx + (size_t)Lyr * E_EDGES * D_EDGE,
                r, ct * 64, nf, src, dst, 0);
    } else {
        const int u = blockIdx.x - 1024;
        const int mi = u >> 4;
        const int matIdx[9] = {1, 2, 3, 4, 6, 7, 8, 9, 10};
        const float* Ws[9] = {Wq1, Wk1, Wv1, Wo1, Wq2, Wk2, Wv2, Wo2, Wc1};
        const int mat = matIdx[mi];
        split_unit(smem, Ws[mi], hiT + (size_t)mat * 65536,
                   loT + (size_t)mat * 65536, u & 15);
    }
}

// q/k/v fused: 1536 blocks = one 6/CU pass; row-panel pinned to one XCD.
__global__ __launch_bounds__(256) void gemm_qkv32(
    const float* __restrict__ ef_in, const float* __restrict__ ctx,
    const short* __restrict__ whiT, const short* __restrict__ wloT,
    const float* __restrict__ bq, const float* __restrict__ bk,
    const float* __restrict__ bv,
    float* __restrict__ qb, float* __restrict__ kb, float* __restrict__ vb,
    int wbase)
{
    __shared__ __attribute__((aligned(16))) char smem[26624];
    const int lid = blockIdx.x;
    const int g = lid & 7, s = lid >> 3;           // s in [0,192)
    const int rowt = g * 16 + s / 12;              // [0,128)
    const int rem = s % 12, wsel = rem >> 2, ct = rem & 3;
    const short* BH = whiT + (size_t)(wbase + 1 + wsel) * 65536;
    const short* BL = wloT + (size_t)(wbase + 1 + wsel) * 65536;
    const float* bias = (wsel == 0) ? bq : (wsel == 1) ? bk : bv;
    float* C = (wsel == 0) ? qb : (wsel == 1) ? kb : vb;
    mcore32(smem, ef_in, ctx, BH, BL, bias, nullptr, nullptr, C,
            rowt * 32, ct * 64, nullptr, nullptr, nullptr, 0);
}

// Generic 512-block GEMM: C = act(A@B + bias + res + res2).
__global__ __launch_bounds__(256) void gemm_g32(
    const float* __restrict__ A, const short* __restrict__ BhiT,
    const short* __restrict__ BloT, const float* __restrict__ bias,
    const float* __restrict__ res, const float* __restrict__ res2,
    float* __restrict__ C, int act)
{
    __shared__ __attribute__((aligned(16))) char smem[26624];
    const int lid = blockIdx.x;
    const int g = lid & 7, s = lid >> 3;           // s in [0,64)
    const int rowt = g * 16 + (s >> 2);            // [0,128)
    const int ct = s & 3;
    mcore32(smem, A, nullptr, BhiT, BloT, bias, res, res2, C,
            rowt * 32, ct * 64, nullptr, nullptr, nullptr, act);
}

// ---------------------------------------------------------------------------
// Sparse attention v6: R15's v5 (wave = edge, 16-lane group = head, no
// cross-group merge) with a 4-WAY unrolled candidate loop — 4 independent
// shfl-reduce chains, ONE joint max + rescale per 4 candidates (halves the
// serial online-softmax update count vs 2-way).
// ---------------------------------------------------------------------------
__global__ __launch_bounds__(256) void attn_sparse6(
    const float* __restrict__ q, const float* __restrict__ k,
    const float* __restrict__ v, const int* __restrict__ cand,
    const int* __restrict__ ccount, float* __restrict__ out)
{
    __shared__ int lc[4][CAP];
    const int t = threadIdx.x;
    const int w = t >> 6, lane = t & 63;
    const int e = blockIdx.x * 4 + w;
    const int h = lane >> 4, il = lane & 15;
    const int m = ccount[e];
    for (int i = lane; i < m; i += 64) lc[w][i] = cand[(size_t)e * CAP + i];

    const float4 q4 = *(const float4*)&q[(size_t)e * D_EDGE + h * HD + il * 4];
    float M = -1e30f, L = 0.f;
    float4 O = make_float4(0.f, 0.f, 0.f, 0.f);

    int i = 0;
    for (; i + 4 <= m; i += 4) {
        const int f0 = lc[w][i], f1 = lc[w][i + 1];
        const int f2 = lc[w][i + 2], f3 = lc[w][i + 3];
        const float4 k0 = *(const float4*)&k[(size_t)f0 * D_EDGE + h * HD + il * 4];
        const float4 v0 = *(const float4*)&v[(size_t)f0 * D_EDGE + h * HD + il * 4];
        const float4 k1 = *(const float4*)&k[(size_t)f1 * D_EDGE + h * HD + il * 4];
        const float4 v1 = *(const float4*)&v[(size_t)f1 * D_EDGE + h * HD + il * 4];
        const float4 k2 = *(const float4*)&k[(size_t)f2 * D_EDGE + h * HD + il * 4];
        const float4 v2 = *(const float4*)&v[(size_t)f2 * D_EDGE + h * HD + il * 4];
        const float4 k3 = *(const float4*)&k[(size_t)f3 * D_EDGE + h * HD + il * 4];
        const float4 v3 = *(const float4*)&v[(size_t)f3 * D_EDGE + h * HD + il * 4];
        float s0 = q4.x * k0.x + q4.y * k0.y + q4.z * k0.z + q4.w * k0.w;
        float s1 = q4.x * k1.x + q4.y * k1.y + q4.z * k1.z + q4.w * k1.w;
        float s2 = q4.x * k2.x + q4.y * k2.y + q4.z * k2.z + q4.w * k2.w;
        float s3 = q4.x * k3.x + q4.y * k3.y + q4.z * k3.z + q4.w * k3.w;
        s0 += __shfl_xor(s0, 1); s1 += __shfl_xor(s1, 1);
        s2 += __shfl_xor(s2, 1); s3 += __shfl_xor(s3, 1);
        s0 += __shfl_xor(s0, 2); s1 += __shfl_xor(s1, 2);
        s2 += __shfl_xor(s2, 2); s3 += __shfl_xor(s3, 2);
        s0 += __shfl_xor(s0, 4); s1 += __shfl_xor(s1, 4);
        s2 += __shfl_xor(s2, 4); s3 += __shfl_xor(s3, 4);
        s0 += __shfl_xor(s0, 8); s1 += __shfl_xor(s1, 8);
        s2 += __shfl_xor(s2, 8); s3 += __shfl_xor(s3, 8);
        s0 *= 0.125f; s1 *= 0.125f; s2 *= 0.125f; s3 *= 0.125f;
        const float m01 = fmaxf(s0, s1), m23 = fmaxf(s2, s3);
        const float Mn = fmaxf(M, fmaxf(m01, m23));
        const float al = __expf(M - Mn);
        const float p0 = __expf(s0 - Mn), p1 = __expf(s1 - Mn);
        const float p2 = __expf(s2 - Mn), p3 = __expf(s3 - Mn);
        O.x = O.x * al + p0 * v0.x + p1 * v1.x + p2 * v2.x + p3 * v3.x;
        O.y = O.y * al + p0 * v0.y + p1 * v1.y + p2 * v2.y + p3 * v3.y;
        O.z = O.z * al + p0 * v0.z + p1 * v1.z + p2 * v2.z + p3 * v3.z;
        O.w = O.w * al + p0 * v0.w + p1 * v1.w + p2 * v2.w + p3 * v3.w;
        L = L * al + (p0 + p1) + (p2 + p3);
        M = Mn;
    }
    for (; i < m; ++i) {
        const int f = lc[w][i];
        const float4 kv = *(const float4*)&k[(size_t)f * D_EDGE + h * HD + il * 4];
        const float4 vv = *(const float4*)&v[(size_t)f * D_EDGE + h * HD + il * 4];
        float s = q4.x * kv.x + q4.y * kv.y + q4.z * kv.z + q4.w * kv.w;
        s += __shfl_xor(s, 1);
        s += __shfl_xor(s, 2);
        s += __shfl_xor(s, 4);
        s += __shfl_xor(s, 8);
        s *= 0.125f;
        const float Mn = fmaxf(M, s);
        const float al = __expf(M - Mn);
        const float p = __expf(s - Mn);
        O.x = O.x * al + p * vv.x;
        O.y = O.y * al + p * vv.y;
        O.z = O.z * al + p * vv.z;
        O.w = O.w * al + p * vv.w;
        L = L * al + p;
        M = Mn;
    }
    const float invL = 1.f / L;
    float4 r = make_float4(O.x * invL, O.y * invL, O.z * invL, O.w * invL);
    *(float4*)&out[(size_t)e * D_EDGE + h * HD + il * 4] = r;
}

// ---------------------------------------------------------------------------
// Fused classifier (R11/R15-proven): out = gelu(y@W1+b1)@W2 + b2.
// 256 blocks x 16-row tiles, LDS 35KB -> 4 blocks/CU.
// ---------------------------------------------------------------------------
__global__ __launch_bounds__(256) void gemm_cls(
    const float* __restrict__ y, const short* __restrict__ BhiT,
    const short* __restrict__ BloT, const float* __restrict__ b1,
    const float* __restrict__ W2, const float* __restrict__ b2,
    float* __restrict__ outp)
{
    __shared__ __attribute__((aligned(16))) char smem[35840];
    short* AsH = (short*)smem;                  // 16*40 sh = 1280 B
    short* AsL = (short*)(smem + 1280);
    short* BsH = (short*)(smem + 2560);         // 256*32 sh = 16384 B
    short* BsL = (short*)(smem + 18944);        // -> 35328
    short* hH  = (short*)smem;                  // 16*264 sh = 8448 B (ph 2)
    short* hL  = (short*)(smem + 8448);
    float* W2s = (float*)(smem + 16896);        // 16384 -> 33280

    const int t = threadIdx.x;
    const int w = t >> 6, lane = t & 63, lr = lane & 15, lg = lane >> 4;
    const int m0 = blockIdx.x * 16;

    f32x4 acc[4];
#pragma unroll
    for (int ct = 0; ct < 4; ++ct) acc[ct] = (f32x4){0.f, 0.f, 0.f, 0.f};

    for (int kt = 0; kt < 8; ++kt) {
        const int k0 = kt * 32;
        if (t < 128) {
            const int row = t >> 3, kc = (t & 7) * 4;
            const float4 a4 = *(const float4*)&y[(size_t)(m0 + row) * 256 + k0 + kc];
            const float fv[4] = {a4.x, a4.y, a4.z, a4.w};
#pragma unroll
            for (int j = 0; j < 4; ++j) {
                const unsigned short hb = f2bf(fv[j]);
                AsH[row * 40 + kc + j] = (short)hb;
                AsL[row * 40 + kc + j] = (short)f2bf(fv[j] - bf2f(hb));
            }
        }
#pragma unroll
        for (int p = 0; p < 4; ++p) {
            const int idx = t + 256 * p;
            const int n = idx >> 2, k8 = (idx & 3) * 8;
            gload_lds16(&BhiT[(size_t)n * 256 + k0 + k8], BsH + (size_t)idx * 8);
            gload_lds16(&BloT[(size_t)n * 256 + k0 + k8], BsL + (size_t)idx * 8);
        }
        __syncthreads();
        const short8v aH = *(const short8v*)&AsH[lr * 40 + lg * 8];
        const short8v aL = *(const short8v*)&AsL[lr * 40 + lg * 8];
#pragma unroll
        for (int ct = 0; ct < 4; ++ct) {
            const int c = w * 64 + ct * 16 + lr;
            const short8v bH = *(const short8v*)&BsH[c * 32 + lg * 8];
            const short8v bL = *(const short8v*)&BsL[c * 32 + lg * 8];
            acc[ct] = __builtin_amdgcn_mfma_f32_16x16x32_bf16(aH, bH, acc[ct], 0, 0, 0);
            acc[ct] = __builtin_amdgcn_mfma_f32_16x16x32_bf16(aH, bL, acc[ct], 0, 0, 0);
            acc[ct] = __builtin_amdgcn_mfma_f32_16x16x32_bf16(aL, bH, acc[ct], 0, 0, 0);
        }
        __syncthreads();
    }

#pragma unroll
    for (int ct = 0; ct < 4; ++ct) {
        const int col = w * 64 + ct * 16 + lr;
        const float bb = b1[col];
#pragma unroll
        for (int i = 0; i < 4; ++i) {
            const int row = lg * 4 + i;
            float vv = acc[ct][i] + bb;
            vv = 0.5f * vv * (1.f + erff(vv * 0.70710678118654752f));
            const unsigned short hb = f2bf(vv);
            hH[row * 264 + col] = (short)hb;
            hL[row * 264 + col] = (short)f2bf(vv - bf2f(hb));
        }
    }
#pragma unroll
    for (int p = 0; p < 4; ++p) {
        const int idx = t + 256 * p;
        gload_lds16(&W2[(size_t)idx * 4], W2s + (size_t)idx * 4);
    }
    __syncthreads();

    f32x4 o = {0.f, 0.f, 0.f, 0.f};
#pragma unroll
    for (int kk = 0; kk < 8; ++kk) {
        const short8v aH = *(const short8v*)&hH[lr * 264 + kk * 32 + lg * 8];
        const short8v aL = *(const short8v*)&hL[lr * 264 + kk * 32 + lg * 8];
        short8v bH, bL;
#pragma unroll
        for (int j = 0; j < 8; ++j) {
            const float x = W2s[(size_t)(kk * 32 + lg * 8 + j) * 16 + lr];
            const unsigned short hb = f2bf(x);
            bH[j] = (short)hb; bL[j] = (short)f2bf(x - bf2f(hb));
        }
        o = __builtin_amdgcn_mfma_f32_16x16x32_bf16(aH, bH, o, 0, 0, 0);
        o = __builtin_amdgcn_mfma_f32_16x16x32_bf16(aH, bL, o, 0, 0, 0);
        o = __builtin_amdgcn_mfma_f32_16x16x32_bf16(aL, bH, o, 0, 0, 0);
    }
    if (w == 0) {
#pragma unroll
        for (int i = 0; i < 4; ++i) {
            const int row = m0 + lg * 4 + i;
            outp[(size_t)row * 16 + lr] = o[i] + b2[lr];
        }
    }
}

// ---------------------------------------------------------------------------
extern "C" void kernel_launch(void* const* d_in, const int* in_sizes, int n_in,
                              void* d_out, int out_size, void* d_ws, size_t ws_size,
                              hipStream_t stream)
{
    const float* nf = (const float*)d_in[0];
    const float* ef = (const float*)d_in[1];
    const int* ei = (const int*)d_in[2];
    const int* src = ei;
    const int* dst = ei + E_EDGES;

    const float* a_Wn[2] = {(const float*)d_in[3],  (const float*)d_in[13]};
    const float* a_bn[2] = {(const float*)d_in[4],  (const float*)d_in[14]};
    const float* a_Wq[2] = {(const float*)d_in[5],  (const float*)d_in[15]};
    const float* a_bq[2] = {(const float*)d_in[6],  (const float*)d_in[16]};
    const float* a_Wk[2] = {(const float*)d_in[7],  (const float*)d_in[17]};
    const float* a_bk[2] = {(const float*)d_in[8],  (const float*)d_in[18]};
    const float* a_Wv[2] = {(const float*)d_in[9],  (const float*)d_in[19]};
    const float* a_bv[2] = {(const float*)d_in[10], (const float*)d_in[20]};
    const float* a_Wo[2] = {(const float*)d_in[11], (const float*)d_in[21]};
    const float* a_bo[2] = {(const float*)d_in[12], (const float*)d_in[22]};
    const float* cls_W1 = (const float*)d_in[23];
    const float* cls_b1 = (const float*)d_in[24];
    const float* cls_W2 = (const float*)d_in[25];
    const float* cls_b2 = (const float*)d_in[26];

    const size_t buf = (size_t)E_EDGES * D_EDGE;  // 1M floats = 4MB
    float* ws = (float*)d_ws;
    float* ctx1 = ws + 0 * buf;         // ctx base; ctx2 contiguous
    float* ctx2 = ws + 1 * buf;
    float* qb   = ws + 2 * buf;
    float* kb   = ws + 3 * buf;
    float* vb   = ws + 4 * buf;
    float* ao   = ws + 5 * buf;
    float* y1   = ws + 6 * buf;
    float* y2   = ctx1;                 // ctx1 dead after layer-1 Wo
    int* cand   = (int*)(ws + 7 * buf);            // 4096*128*4 = 2MB
    int* ccount = cand + (size_t)E_EDGES * CAP;    // 16KB
    short* whiT = (short*)(ccount + E_EDGES);      // 11 x 128KB
    short* wloT = whiT + (size_t)11 * 65536;       // 11 x 128KB

    // A: adjacency + Wn splits (the only splits ctx needs)
    adj_prep<<<1056, 256, 0, stream>>>(src, dst, cand, ccount,
                                       a_Wn[0], a_Wn[1], whiT, wloT);
    // B: ctx both layers + the 9 remaining splits (first needed by qkv)
    ctx_prep<<<1168, 256, 0, stream>>>(nf, src, dst, whiT, wloT,
                                       a_bn[0], a_bn[1], ctx1,
                                       a_Wq[0], a_Wk[0], a_Wv[0], a_Wo[0],
                                       a_Wq[1], a_Wk[1], a_Wv[1], a_Wo[1],
                                       cls_W1);

    const float* ef_in = ef;
    const float* ctxL[2] = {ctx1, ctx2};
    float* yout[2] = {y1, y2};
    for (int L = 0; L < 2; ++L) {
        const int wbase = L * 5;
        gemm_qkv32<<<1536, 256, 0, stream>>>(
            ef_in, ctxL[L], whiT, wloT, a_bq[L], a_bk[L], a_bv[L],
            qb, kb, vb, wbase);
        attn_sparse6<<<E_EDGES / 4, 256, 0, stream>>>(qb, kb, vb, cand, ccount, ao);
        gemm_g32<<<512, 256, 0, stream>>>(
            ao, whiT + (size_t)(wbase + 4) * 65536,
            wloT + (size_t)(wbase + 4) * 65536,
            a_bo[L], ef_in, ctxL[L], yout[L], 0);
        ef_in = yout[L];
    }

    // classifier (fused): out = gelu(y2@W1+b1)@W2 + b2
    gemm_cls<<<E_EDGES / 16, 256, 0, stream>>>(
        y2, whiT + (size_t)10 * 65536, wloT + (size_t)10 * 65536,
        cls_b1, cls_W2, cls_b2, (float*)d_out);
}

// Round 20
// 123.212 us; speedup vs baseline: 1.0321x; 1.0290x over previous
//
#include <hip/hip_runtime.h>
#include <math.h>

#define E_EDGES 4096
#define N_NODES 1024
#define D_NODE 128
#define D_EDGE 256
#define HEADS 4
#define HD 64
#define N_CLASSES 16
#define CAP 128   // max adjacent edges per edge (avg ~16, worst ~50)

typedef __attribute__((ext_vector_type(8))) short short8v;  // 8 bf16 = 4 VGPR
typedef __attribute__((ext_vector_type(4))) short short4v;  // 4 bf16 = 2 VGPR
typedef __attribute__((ext_vector_type(4))) float f32x4;    // MFMA C/D frag

__device__ __forceinline__ unsigned short f2bf(float f) {
    unsigned u = __float_as_uint(f);
    return (unsigned short)((u + 0x7FFFu + ((u >> 16) & 1u)) >> 16);
}
__device__ __forceinline__ float bf2f(unsigned short b) {
    return __uint_as_float(((unsigned)b) << 16);
}

// direct-to-LDS 16B DMA (gfx950): per-wave dest = uniform base + lane*16.
__device__ __forceinline__ void gload_lds16(const void* g, void* l) {
    __builtin_amdgcn_global_load_lds((const __attribute__((address_space(1))) void*)g,
                                     (__attribute__((address_space(3))) void*)l, 16, 0, 0);
}

// ---------------------------------------------------------------------------
// Weight-split unit: one 64x64 tile of one f32 W[k][n] -> TRANSPOSED bf16
// hi/lo WT[n][k], coalesced via LDS transpose. Uses smem[0..16639].
// ---------------------------------------------------------------------------
__device__ __forceinline__ void split_unit(
    char* smem, const float* __restrict__ W, short* __restrict__ ho,
    short* __restrict__ lo, int tile)
{
    float* tl = (float*)smem;   // [64][65]
    const int t = threadIdx.x;
    const int k0 = (tile >> 2) * 64, n0 = (tile & 3) * 64;
#pragma unroll
    for (int p = 0; p < 4; ++p) {
        const int kr = (t >> 4) + p * 16;
        const int nc = (t & 15) * 4;
        *(float4*)&tl[kr * 65 + nc] = *(const float4*)&W[(size_t)(k0 + kr) * 256 + n0 + nc];
    }
    __syncthreads();
    const int n = t >> 2, ks = (t & 3) * 16;
    short8v h0, h1, l0, l1;
#pragma unroll
    for (int j = 0; j < 8; ++j) {
        const float x = tl[(ks + j) * 65 + n];
        const unsigned short hb = f2bf(x);
        h0[j] = (short)hb; l0[j] = (short)f2bf(x - bf2f(hb));
    }
#pragma unroll
    for (int j = 0; j < 8; ++j) {
        const float x = tl[(ks + 8 + j) * 65 + n];
        const unsigned short hb = f2bf(x);
        h1[j] = (short)hb; l1[j] = (short)f2bf(x - bf2f(hb));
    }
    *(short8v*)&ho[(size_t)(n0 + n) * 256 + k0 + ks] = h0;
    *(short8v*)&ho[(size_t)(n0 + n) * 256 + k0 + ks + 8] = h1;
    *(short8v*)&lo[(size_t)(n0 + n) * 256 + k0 + ks] = l0;
    *(short8v*)&lo[(size_t)(n0 + n) * 256 + k0 + ks + 8] = l1;
}

// ---------------------------------------------------------------------------
// Adjacency unit: one wave builds edge e's CSR list (ballot-compaction asc).
// ---------------------------------------------------------------------------
__device__ __forceinline__ void adj_unit(
    const int* __restrict__ src, const int* __restrict__ dst,
    int* __restrict__ cand, int* __restrict__ ccount, int e, int lane)
{
    const int a = src[e], b = dst[e];
    int* my = cand + (size_t)e * CAP;
    int base = 0;
    for (int c0 = 0; c0 < E_EDGES; c0 += 64) {
        const int f = c0 + lane;
        const int sf = src[f], df = dst[f];
        const bool adj = (sf == a) | (sf == b) | (df == a) | (df == b);
        const unsigned long long mk = __ballot(adj);
        if (adj) {
            const int pos = base + __popcll(mk & ((1ull << lane) - 1ull));
            if (pos < CAP) my[pos] = f;
        }
        base += __popcll(mk);
    }
    if (lane == 0) ccount[e] = (base < CAP) ? base : CAP;
}

// ---------------------------------------------------------------------------
// Split-bf16 MFMA GEMM core, BM=32 (R13/R15-proven).
// C[32x64] = act((A[+A2])@B + bias + r1 + r2), K=256.
// A@B = AhBh + AhBl + AlBh. 4 waves (2x2), wave = 16x32 out, 6 MFMAs/K-tile
// in 2 independent acc chains. LDS 26.6KB. Dbuf, ONE barrier/K-tile;
// A loads before MFMA, split after (T14); B via global_load_lds DMA.
// If nf: A row m = concat(nf[src[m]], nf[dst[m]]).
// ---------------------------------------------------------------------------
__device__ __forceinline__ void mcore32(
    char* smem,
    const float* __restrict__ A, const float* __restrict__ A2,
    const short* __restrict__ BhiT, const short* __restrict__ BloT,
    const float* __restrict__ bias, const float* __restrict__ res,
    const float* __restrict__ res2, float* __restrict__ C,
    int m0, int n0,
    const float* __restrict__ nf, const int* __restrict__ src,
    const int* __restrict__ dst, int act)
{
    short* AsH = (short*)smem;              // [2][32*40]  5120 B
    short* AsL = (short*)(smem + 5120);     //             5120 B
    short* BsH = (short*)(smem + 10240);    // [2][64*32]  8192 B
    short* BsL = (short*)(smem + 18432);    //             8192 B -> 26624
    const int t = threadIdx.x;
    const int w = t >> 6, lane = t & 63, lr = lane & 15, lg = lane >> 4;
    const int WR = (w >> 1) * 16, WC = (w & 1) * 32;
    const int ar = t >> 3, akc = (t & 7) * 4;   // A stage: row, k-col
    const int bn = t >> 2, bkc = (t & 3) * 8;   // B DMA: n-row, k-col

    int nS = 0, nD = 0;
    if (nf) { nS = src[m0 + ar]; nD = dst[m0 + ar]; }

    f32x4 acc0 = {0.f, 0.f, 0.f, 0.f}, acc1 = {0.f, 0.f, 0.f, 0.f};
    float4 av;

#define LOADA_R(k0)                                                            \
    do {                                                                       \
        const int kq = (k0) + akc;                                             \
        if (nf) {                                                              \
            const float* pp = (kq < D_NODE)                                    \
                ? &nf[(size_t)nS * D_NODE + kq]                                \
                : &nf[(size_t)nD * D_NODE + kq - D_NODE];                      \
            av = *(const float4*)pp;                                           \
        } else {                                                               \
            av = *(const float4*)&A[(size_t)(m0 + ar) * 256 + kq];             \
            if (A2) {                                                          \
                const float4 c_ = *(const float4*)&A2[(size_t)(m0 + ar) * 256 + kq]; \
                av.x += c_.x; av.y += c_.y; av.z += c_.z; av.w += c_.w;        \
            }                                                                  \
        }                                                                      \
    } while (0)
#define STOREA_S(buf)                                                          \
    do {                                                                       \
        short4v ah, al;                                                        \
        const float fv[4] = {av.x, av.y, av.z, av.w};                          \
        _Pragma("unroll") for (int j = 0; j < 4; ++j) {                        \
            const unsigned short hb = f2bf(fv[j]);                             \
            ah[j] = (short)hb; al[j] = (short)f2bf(fv[j] - bf2f(hb));          \
        }                                                                      \
        *(short4v*)&AsH[(buf) * 1280 + ar * 40 + akc] = ah;                    \
        *(short4v*)&AsL[(buf) * 1280 + ar * 40 + akc] = al;                    \
    } while (0)
#define STAGE_B(buf, k0)                                                       \
    do {                                                                       \
        gload_lds16(&BhiT[(size_t)(n0 + bn) * 256 + (k0) + bkc],               \
                    BsH + (buf) * 2048 + t * 8);                               \
        gload_lds16(&BloT[(size_t)(n0 + bn) * 256 + (k0) + bkc],               \
                    BsL + (buf) * 2048 + t * 8);                               \
    } while (0)
#define MFMA_STEP(buf)                                                         \
    do {                                                                       \
        const int c0 = WC + lr, c1 = WC + 16 + lr;                             \
        const short8v bH0 = *(const short8v*)&BsH[(buf) * 2048 + c0 * 32 + lg * 8]; \
        const short8v bL0 = *(const short8v*)&BsL[(buf) * 2048 + c0 * 32 + lg * 8]; \
        const short8v bH1 = *(const short8v*)&BsH[(buf) * 2048 + c1 * 32 + lg * 8]; \
        const short8v bL1 = *(const short8v*)&BsL[(buf) * 2048 + c1 * 32 + lg * 8]; \
        const short8v aH = *(const short8v*)&AsH[(buf) * 1280 + (WR + lr) * 40 + lg * 8]; \
        const short8v aL = *(const short8v*)&AsL[(buf) * 1280 + (WR + lr) * 40 + lg * 8]; \
        acc0 = __builtin_amdgcn_mfma_f32_16x16x32_bf16(aH, bH0, acc0, 0, 0, 0);\
        acc1 = __builtin_amdgcn_mfma_f32_16x16x32_bf16(aH, bH1, acc1, 0, 0, 0);\
        acc0 = __builtin_amdgcn_mfma_f32_16x16x32_bf16(aH, bL0, acc0, 0, 0, 0);\
        acc1 = __builtin_amdgcn_mfma_f32_16x16x32_bf16(aH, bL1, acc1, 0, 0, 0);\
        acc0 = __builtin_amdgcn_mfma_f32_16x16x32_bf16(aL, bH0, acc0, 0, 0, 0);\
        acc1 = __builtin_amdgcn_mfma_f32_16x16x32_bf16(aL, bH1, acc1, 0, 0, 0);\
    } while (0)

    LOADA_R(0);
    STAGE_B(0, 0);
    STOREA_S(0);
    __syncthreads();

    for (int kt = 0; kt < 8; ++kt) {       // K = 256 = 8 x 32
        const int cur = kt & 1;
        if (kt < 7) {
            STAGE_B(cur ^ 1, (kt + 1) * 32);
            LOADA_R((kt + 1) * 32);
        }
        MFMA_STEP(cur);
        if (kt < 7) STOREA_S(cur ^ 1);
        __syncthreads();
    }

#define EPI(accv, ct)                                                          \
    do {                                                                       \
        const int col = n0 + WC + (ct) * 16 + lr;                              \
        const float bb = bias ? bias[col] : 0.f;                               \
        _Pragma("unroll") for (int i = 0; i < 4; ++i) {                        \
            const int row = m0 + WR + lg * 4 + i;                              \
            float v = accv[i] + bb;                                            \
            if (res)  v += res[(size_t)row * D_EDGE + col];                    \
            if (res2) v += res2[(size_t)row * D_EDGE + col];                   \
            if (act == 1) v = 0.5f * v * (1.f + erff(v * 0.70710678118654752f)); \
            C[(size_t)row * D_EDGE + col] = v;                                 \
        }                                                                      \
    } while (0)
    EPI(acc0, 0); EPI(acc1, 1);
#undef LOADA_R
#undef STOREA_S
#undef STAGE_B
#undef MFMA_STEP
#undef EPI
}

// ---------------------------------------------------------------------------
// Dispatch A: adjacency (blocks 0..1023, wave per edge) + Wn1/Wn2 splits
// (blocks 1024..1055) — only the splits ctx needs.
// ---------------------------------------------------------------------------
__global__ __launch_bounds__(256) void adj_prep(
    const int* __restrict__ src, const int* __restrict__ dst,
    int* __restrict__ cand, int* __restrict__ ccount,
    const float* Wn1, const float* Wn2, short* hiT, short* loT)
{
    __shared__ __attribute__((aligned(16))) char smem[16640];
    if (blockIdx.x < 1024) {
        const int t = threadIdx.x;
        adj_unit(src, dst, cand, ccount, blockIdx.x * 4 + (t >> 6), t & 63);
    } else {
        const int u = blockIdx.x - 1024;
        const int mat = (u >> 4) ? 5 : 0;
        split_unit(smem, (u >> 4) ? Wn2 : Wn1,
                   hiT + (size_t)mat * 65536, loT + (size_t)mat * 65536, u & 15);
    }
}

// ---------------------------------------------------------------------------
// Dispatch B: ctx both layers (blocks 0..1023, XCD row-panel pinned) + the
// 9 remaining weight splits (blocks 1024..1167).
// ---------------------------------------------------------------------------
__global__ __launch_bounds__(256) void ctx_prep(
    const float* __restrict__ nf, const int* __restrict__ src,
    const int* __restrict__ dst, short* hiT, short* loT,
    const float* __restrict__ bn1, const float* __restrict__ bn2,
    float* __restrict__ ctx,
    const float* Wq1, const float* Wk1, const float* Wv1, const float* Wo1,
    const float* Wq2, const float* Wk2, const float* Wv2, const float* Wo2,
    const float* Wc1)
{
    __shared__ __attribute__((aligned(16))) char smem[26624];
    if (blockIdx.x < 1024) {
        const int lid = blockIdx.x;
        const int g = lid & 7, s = lid >> 3;       // XCD, slot
        const int rowt = g * 32 + (s >> 2);        // [0,256)
        const int ct = s & 3;
        const int R = rowt * 32;
        const int Lyr = R >> 12;
        const int r = R & (E_EDGES - 1);
        mcore32(smem, nullptr, nullptr,
                hiT + (size_t)(Lyr * 5) * 65536, loT + (size_t)(Lyr * 5) * 65536,
                Lyr ? bn2 : bn1, nullptr, nullptr,
                ctx + (size_t)Lyr * E_EDGES * D_EDGE,
                r, ct * 64, nf, src, dst, 0);
    } else {
        const int u = blockIdx.x - 1024;
        const int mi = u >> 4;
        const int matIdx[9] = {1, 2, 3, 4, 6, 7, 8, 9, 10};
        const float* Ws[9] = {Wq1, Wk1, Wv1, Wo1, Wq2, Wk2, Wv2, Wo2, Wc1};
        const int mat = matIdx[mi];
        split_unit(smem, Ws[mi], hiT + (size_t)mat * 65536,
                   loT + (size_t)mat * 65536, u & 15);
    }
}

// q/k/v fused: 1536 blocks = one 6/CU pass; row-panel pinned to one XCD.
__global__ __launch_bounds__(256) void gemm_qkv32(
    const float* __restrict__ ef_in, const float* __restrict__ ctx,
    const short* __restrict__ whiT, const short* __restrict__ wloT,
    const float* __restrict__ bq, const float* __restrict__ bk,
    const float* __restrict__ bv,
    float* __restrict__ qb, float* __restrict__ kb, float* __restrict__ vb,
    int wbase)
{
    __shared__ __attribute__((aligned(16))) char smem[26624];
    const int lid = blockIdx.x;
    const int g = lid & 7, s = lid >> 3;           // s in [0,192)
    const int rowt = g * 16 + s / 12;              // [0,128)
    const int rem = s % 12, wsel = rem >> 2, ct = rem & 3;
    const short* BH = whiT + (size_t)(wbase + 1 + wsel) * 65536;
    const short* BL = wloT + (size_t)(wbase + 1 + wsel) * 65536;
    const float* bias = (wsel == 0) ? bq : (wsel == 1) ? bk : bv;
    float* C = (wsel == 0) ? qb : (wsel == 1) ? kb : vb;
    mcore32(smem, ef_in, ctx, BH, BL, bias, nullptr, nullptr, C,
            rowt * 32, ct * 64, nullptr, nullptr, nullptr, 0);
}

// Generic 512-block GEMM: C = act(A@B + bias + res + res2).
__global__ __launch_bounds__(256) void gemm_g32(
    const float* __restrict__ A, const short* __restrict__ BhiT,
    const short* __restrict__ BloT, const float* __restrict__ bias,
    const float* __restrict__ res, const float* __restrict__ res2,
    float* __restrict__ C, int act)
{
    __shared__ __attribute__((aligned(16))) char smem[26624];
    const int lid = blockIdx.x;
    const int g = lid & 7, s = lid >> 3;           // s in [0,64)
    const int rowt = g * 16 + (s >> 2);            // [0,128)
    const int ct = s & 3;
    mcore32(smem, A, nullptr, BhiT, BloT, bias, res, res2, C,
            rowt * 32, ct * 64, nullptr, nullptr, nullptr, act);
}

// ---------------------------------------------------------------------------
// Sparse attention v5 (R15-proven). 1024 blocks x 4 waves; WAVE = EDGE,
// 16-lane group = head. Independent per-head online softmax, no merge.
// ---------------------------------------------------------------------------
__global__ __launch_bounds__(256) void attn_sparse5(
    const float* __restrict__ q, const float* __restrict__ k,
    const float* __restrict__ v, const int* __restrict__ cand,
    const int* __restrict__ ccount, float* __restrict__ out)
{
    __shared__ int lc[4][CAP];
    const int t = threadIdx.x;
    const int w = t >> 6, lane = t & 63;
    const int e = blockIdx.x * 4 + w;
    const int h = lane >> 4, il = lane & 15;
    const int m = ccount[e];
    for (int i = lane; i < m; i += 64) lc[w][i] = cand[(size_t)e * CAP + i];

    const float4 q4 = *(const float4*)&q[(size_t)e * D_EDGE + h * HD + il * 4];
    float M = -1e30f, L = 0.f;
    float4 O = make_float4(0.f, 0.f, 0.f, 0.f);

    int i = 0;
    for (; i + 2 <= m; i += 2) {
        const int f0 = lc[w][i], f1 = lc[w][i + 1];
        const float4 k0 = *(const float4*)&k[(size_t)f0 * D_EDGE + h * HD + il * 4];
        const float4 v0 = *(const float4*)&v[(size_t)f0 * D_EDGE + h * HD + il * 4];
        const float4 k1 = *(const float4*)&k[(size_t)f1 * D_EDGE + h * HD + il * 4];
        const float4 v1 = *(const float4*)&v[(size_t)f1 * D_EDGE + h * HD + il * 4];
        float s0 = q4.x * k0.x + q4.y * k0.y + q4.z * k0.z + q4.w * k0.w;
        float s1 = q4.x * k1.x + q4.y * k1.y + q4.z * k1.z + q4.w * k1.w;
        s0 += __shfl_xor(s0, 1); s1 += __shfl_xor(s1, 1);
        s0 += __shfl_xor(s0, 2); s1 += __shfl_xor(s1, 2);
        s0 += __shfl_xor(s0, 4); s1 += __shfl_xor(s1, 4);
        s0 += __shfl_xor(s0, 8); s1 += __shfl_xor(s1, 8);
        s0 *= 0.125f; s1 *= 0.125f;            // 1/sqrt(64)
        const float Mn = fmaxf(M, fmaxf(s0, s1));
        const float al = __expf(M - Mn);
        const float p0 = __expf(s0 - Mn), p1 = __expf(s1 - Mn);
        O.x = O.x * al + p0 * v0.x + p1 * v1.x;
        O.y = O.y * al + p0 * v0.y + p1 * v1.y;
        O.z = O.z * al + p0 * v0.z + p1 * v1.z;
        O.w = O.w * al + p0 * v0.w + p1 * v1.w;
        L = L * al + p0 + p1;
        M = Mn;
    }
    if (i < m) {
        const int f = lc[w][i];
        const float4 kv = *(const float4*)&k[(size_t)f * D_EDGE + h * HD + il * 4];
        const float4 vv = *(const float4*)&v[(size_t)f * D_EDGE + h * HD + il * 4];
        float s = q4.x * kv.x + q4.y * kv.y + q4.z * kv.z + q4.w * kv.w;
        s += __shfl_xor(s, 1);
        s += __shfl_xor(s, 2);
        s += __shfl_xor(s, 4);
        s += __shfl_xor(s, 8);
        s *= 0.125f;
        const float Mn = fmaxf(M, s);
        const float al = __expf(M - Mn);
        const float p = __expf(s - Mn);
        O.x = O.x * al + p * vv.x;
        O.y = O.y * al + p * vv.y;
        O.z = O.z * al + p * vv.z;
        O.w = O.w * al + p * vv.w;
        L = L * al + p;
        M = Mn;
    }
    const float invL = 1.f / L;
    float4 r = make_float4(O.x * invL, O.y * invL, O.z * invL, O.w * invL);
    *(float4*)&out[(size_t)e * D_EDGE + h * HD + il * 4] = r;
}

// ---------------------------------------------------------------------------
// cls_out: out[4096][16] = h@W2 + b2. 256 blocks x 16 rows; W2 in LDS;
// h from global (L2-warm), split in regs; 24 MFMAs on wave 0.
// ---------------------------------------------------------------------------
__global__ __launch_bounds__(256) void cls_out(
    const float* __restrict__ h, const float* __restrict__ W2,
    const float* __restrict__ b2, float* __restrict__ outp)
{
    __shared__ __attribute__((aligned(16))) float W2s[256 * 16];
    const int t = threadIdx.x;
    const int w = t >> 6, lane = t & 63, lr = lane & 15, lg = lane >> 4;
    const int m0 = blockIdx.x * 16;
#pragma unroll
    for (int p = 0; p < 4; ++p) {
        const int idx = t + 256 * p;       // 1024 x 16B = 16KB
        gload_lds16(&W2[(size_t)idx * 4], W2s + (size_t)idx * 4);
    }
    __syncthreads();
    if (w == 0) {
        f32x4 o = {0.f, 0.f, 0.f, 0.f};
#pragma unroll
        for (int kk = 0; kk < 8; ++kk) {
            const float4 h0 = *(const float4*)&h[(size_t)(m0 + lr) * 256 + kk * 32 + lg * 8];
            const float4 h1 = *(const float4*)&h[(size_t)(m0 + lr) * 256 + kk * 32 + lg * 8 + 4];
            short8v aH, aL;
            const float fv[8] = {h0.x, h0.y, h0.z, h0.w, h1.x, h1.y, h1.z, h1.w};
#pragma unroll
            for (int j = 0; j < 8; ++j) {
                const unsigned short hb = f2bf(fv[j]);
                aH[j] = (short)hb; aL[j] = (short)f2bf(fv[j] - bf2f(hb));
            }
            short8v bH, bL;
#pragma unroll
            for (int j = 0; j < 8; ++j) {
                const float x = W2s[(size_t)(kk * 32 + lg * 8 + j) * 16 + lr];
                const unsigned short hb = f2bf(x);
                bH[j] = (short)hb; bL[j] = (short)f2bf(x - bf2f(hb));
            }
            o = __builtin_amdgcn_mfma_f32_16x16x32_bf16(aH, bH, o, 0, 0, 0);
            o = __builtin_amdgcn_mfma_f32_16x16x32_bf16(aH, bL, o, 0, 0, 0);
            o = __builtin_amdgcn_mfma_f32_16x16x32_bf16(aL, bH, o, 0, 0, 0);
        }
#pragma unroll
        for (int i = 0; i < 4; ++i) {
            const int row = m0 + lg * 4 + i;
            outp[(size_t)row * 16 + lr] = o[i] + b2[lr];
        }
    }
}

// ---------------------------------------------------------------------------
extern "C" void kernel_launch(void* const* d_in, const int* in_sizes, int n_in,
                              void* d_out, int out_size, void* d_ws, size_t ws_size,
                              hipStream_t stream)
{
    const float* nf = (const float*)d_in[0];
    const float* ef = (const float*)d_in[1];
    const int* ei = (const int*)d_in[2];
    const int* src = ei;
    const int* dst = ei + E_EDGES;

    const float* a_Wn[2] = {(const float*)d_in[3],  (const float*)d_in[13]};
    const float* a_bn[2] = {(const float*)d_in[4],  (const float*)d_in[14]};
    const float* a_Wq[2] = {(const float*)d_in[5],  (const float*)d_in[15]};
    const float* a_bq[2] = {(const float*)d_in[6],  (const float*)d_in[16]};
    const float* a_Wk[2] = {(const float*)d_in[7],  (const float*)d_in[17]};
    const float* a_bk[2] = {(const float*)d_in[8],  (const float*)d_in[18]};
    const float* a_Wv[2] = {(const float*)d_in[9],  (const float*)d_in[19]};
    const float* a_bv[2] = {(const float*)d_in[10], (const float*)d_in[20]};
    const float* a_Wo[2] = {(const float*)d_in[11], (const float*)d_in[21]};
    const float* a_bo[2] = {(const float*)d_in[12], (const float*)d_in[22]};
    const float* cls_W1 = (const float*)d_in[23];
    const float* cls_b1 = (const float*)d_in[24];
    const float* cls_W2 = (const float*)d_in[25];
    const float* cls_b2 = (const float*)d_in[26];

    const size_t buf = (size_t)E_EDGES * D_EDGE;  // 1M floats = 4MB
    float* ws = (float*)d_ws;
    float* ctx1 = ws + 0 * buf;         // ctx base; ctx2 contiguous
    float* ctx2 = ws + 1 * buf;
    float* qb   = ws + 2 * buf;         // later aliased by h (post attn L2)
    float* kb   = ws + 3 * buf;
    float* vb   = ws + 4 * buf;
    float* ao   = ws + 5 * buf;
    float* y1   = ws + 6 * buf;
    float* y2   = ctx1;                 // ctx1 dead after layer-1 Wo
    float* hb   = qb;                   // qb dead after layer-2 attn
    int* cand   = (int*)(ws + 7 * buf);            // 4096*128*4 = 2MB
    int* ccount = cand + (size_t)E_EDGES * CAP;    // 16KB
    short* whiT = (short*)(ccount + E_EDGES);      // 11 x 128KB
    short* wloT = whiT + (size_t)11 * 65536;       // 11 x 128KB

    // A: adjacency + Wn splits (the only splits ctx needs)
    adj_prep<<<1056, 256, 0, stream>>>(src, dst, cand, ccount,
                                       a_Wn[0], a_Wn[1], whiT, wloT);
    // B: ctx both layers + the 9 remaining splits (first needed by qkv)
    ctx_prep<<<1168, 256, 0, stream>>>(nf, src, dst, whiT, wloT,
                                       a_bn[0], a_bn[1], ctx1,
                                       a_Wq[0], a_Wk[0], a_Wv[0], a_Wo[0],
                                       a_Wq[1], a_Wk[1], a_Wv[1], a_Wo[1],
                                       cls_W1);

    const float* ef_in = ef;
    const float* ctxL[2] = {ctx1, ctx2};
    float* yout[2] = {y1, y2};
    for (int L = 0; L < 2; ++L) {
        const int wbase = L * 5;
        gemm_qkv32<<<1536, 256, 0, stream>>>(
            ef_in, ctxL[L], whiT, wloT, a_bq[L], a_bk[L], a_bv[L],
            qb, kb, vb, wbase);
        attn_sparse5<<<E_EDGES / 4, 256, 0, stream>>>(qb, kb, vb, cand, ccount, ao);
        gemm_g32<<<512, 256, 0, stream>>>(
            ao, whiT + (size_t)(wbase + 4) * 65536,
            wloT + (size_t)(wbase + 4) * 65536,
            a_bo[L], ef_in, ctxL[L], yout[L], 0);
        ef_in = yout[L];
    }

    // classifier: h = gelu(y2@W1+b1); out = h@W2 + b2
    gemm_g32<<<512, 256, 0, stream>>>(
        y2, whiT + (size_t)10 * 65536, wloT + (size_t)10 * 65536,
        cls_b1, nullptr, nullptr, hb, 1);
    cls_out<<<E_EDGES / 16, 256, 0, stream>>>(hb, cls_W2, cls_b2, (float*)d_out);
}